// Round 2
// baseline (234.797 us; speedup 1.0000x reference)
//
#include <hip/hip_runtime.h>
#include <math.h>

#define T_LEN 1024
#define L_LEN 64
#define D_DIM 16
#define PADW  20                      // words per staged x-column: 16 data + 4 pad (80B = 5*16B, float4-aligned)
#define NSTEP (T_LEN + L_LEN - 1)     // 1087 wavefront steps
#define BIGV  1e30f

// One wave64 per (b,p) pair. lane = pattern row l. Anti-diagonal wavefront over t.
// Block = 256 threads = 4 waves = 4 consecutive p for one b. Grid = 16 b * 16 pgroups = 256 blocks
// = 1024 waves = 1 wave per SIMD chip-wide.
__global__ __launch_bounds__(256) void dtw_wavefront(
    const float* __restrict__ x,      // (16, 16, 1024)
    const float* __restrict__ patts,  // (64, 16, 64)
    float* __restrict__ out,          // (16, 64, 64, 64)
    float w) {
  __shared__ float xs[T_LEN * PADW + T_LEN];  // 84 KiB: x columns + x2[t]

  const int tid  = threadIdx.x;
  const int lane = tid & 63;
  const int wv   = tid >> 6;
  const int b    = blockIdx.x >> 4;
  const int pg   = blockIdx.x & 15;
  const int p    = pg * 4 + wv;

  // ---- stage x[b] into LDS as [t][dd] (padded), coalesced global reads ----
  const float* xb = x + b * (D_DIM * T_LEN);
  for (int k = 0; k < (D_DIM * T_LEN) / 256; ++k) {
    int idx = k * 256 + tid;
    int dd = idx >> 10;               // x layout is [dd][t]
    int t  = idx & (T_LEN - 1);
    xs[t * PADW + dd] = xb[idx];
  }
  __syncthreads();
  // x2[t] = ||x[:,t]||^2
  for (int k = 0; k < T_LEN / 256; ++k) {
    int t = k * 256 + tid;
    float s2 = 0.f;
    #pragma unroll
    for (int dd = 0; dd < D_DIM; ++dd) { float v = xs[t * PADW + dd]; s2 = fmaf(v, v, s2); }
    xs[T_LEN * PADW + t] = s2;
  }
  __syncthreads();

  // ---- lane-resident pattern column p[:, lane] and its squared norm ----
  float pv[D_DIM];
  float p2 = 0.f;
  #pragma unroll
  for (int dd = 0; dd < D_DIM; ++dd) {
    float v = patts[p * (D_DIM * L_LEN) + dd * L_LEN + lane];
    pv[dd] = v;
    p2 = fmaf(v, v, p2);
  }

  float* op = out + ((b * 64 + p) * 64 + lane) * 64;  // row base for this lane's outputs

  const int permaddr = ((lane - 1) & 63) << 2;        // ds_bpermute: pull from lane-1 (lane0 garbage, overridden)

  float prev = BIGV;   // D[l][t-1]   (own, last step)
  float shA  = BIGV;   // D[l-1][t]   (lane-1, last step)
  float shB  = BIGV;   // D[l-1][t-1] (lane-1, two steps ago)

  // preload column for s=0 (t = -lane, clamped; garbage unused by inactive lanes)
  int tc0 = (0 - lane) < 0 ? 0 : (0 - lane);
  float4 c0 = *(const float4*)&xs[tc0 * PADW + 0];
  float4 c1 = *(const float4*)&xs[tc0 * PADW + 4];
  float4 c2 = *(const float4*)&xs[tc0 * PADW + 8];
  float4 c3 = *(const float4*)&xs[tc0 * PADW + 12];
  float  cx2 = xs[T_LEN * PADW + tc0];

  for (int s = 0; s < NSTEP; ++s) {
    const int t = s - lane;

    // consume current column, prefetch next (hides LDS latency one step ahead)
    float4 u0 = c0, u1 = c1, u2 = c2, u3 = c3;
    float  ux2 = cx2;
    int tn  = t + 1;
    int tcn = tn < 0 ? 0 : (tn > T_LEN - 1 ? T_LEN - 1 : tn);
    c0 = *(const float4*)&xs[tcn * PADW + 0];
    c1 = *(const float4*)&xs[tcn * PADW + 4];
    c2 = *(const float4*)&xs[tcn * PADW + 8];
    c3 = *(const float4*)&xs[tcn * PADW + 12];
    cx2 = xs[T_LEN * PADW + tcn];

    // dist = sqrt(max(x2 + p2 - 2*dot, 1e-12)) ; 4 independent FMA chains for ILP
    float d0 = fmaf(u0.x, pv[0],  fmaf(u0.y, pv[1],  fmaf(u0.z, pv[2],  u0.w * pv[3])));
    float d1 = fmaf(u1.x, pv[4],  fmaf(u1.y, pv[5],  fmaf(u1.z, pv[6],  u1.w * pv[7])));
    float d2 = fmaf(u2.x, pv[8],  fmaf(u2.y, pv[9],  fmaf(u2.z, pv[10], u2.w * pv[11])));
    float d3 = fmaf(u3.x, pv[12], fmaf(u3.y, pv[13], fmaf(u3.z, pv[14], u3.w * pv[15])));
    float dot  = (d0 + d1) + (d2 + d3);
    float sq   = fmaf(-2.f, dot, ux2 + p2);
    float dist = sqrtf(fmaxf(sq, 1e-12f));

    // DP cell: min over 3 predecessors, BIG-sentinel semantics identical to reference
    float m   = fminf(fminf(prev, shA), shB);        // v_min3_f32
    float wm  = (m >= 0.5e30f) ? 0.f : w * m;        // only BIG at cell (0,0)
    float val = dist + wm;
    float cur = ((unsigned)t < (unsigned)T_LEN) ? val : BIGV;

    // store last 64 columns
    if ((unsigned)(t - (T_LEN - L_LEN)) < (unsigned)L_LEN) op[t - (T_LEN - L_LEN)] = val;

    // pass cur down one lane for next step
    int sh = __builtin_amdgcn_ds_bpermute(permaddr, __float_as_int(cur));
    shB = shA;
    shA = (lane == 0) ? BIGV : __int_as_float(sh);
    prev = cur;
  }
}

extern "C" void kernel_launch(void* const* d_in, const int* in_sizes, int n_in,
                              void* d_out, int out_size, void* d_ws, size_t ws_size,
                              hipStream_t stream) {
  const float* x     = (const float*)d_in[0];
  const float* patts = (const float*)d_in[1];
  float* out         = (float*)d_out;
  const float w = (float)exp(log(0.1) / 64.0);  // RHO ** (1/L), matches reference double->f32
  dim3 grid(256), block(256);
  hipLaunchKernelGGL(dtw_wavefront, grid, block, 0, stream, x, patts, out, w);
}

// Round 3
// 77.432 us; speedup vs baseline: 3.0323x; 3.0323x over previous
//
#include <hip/hip_runtime.h>
#include <math.h>

typedef _Float16 h2 __attribute__((ext_vector_type(2)));
typedef unsigned int u32;

#define T_LEN 1024
#define L_LEN 64
#define BIGV  1e30f

// LDS: x columns as 16 f16 (32B) padded to 48B stride (even 32-bank coverage for
// b128 reads at per-lane t = s - lane), plus separate f32 x2[t] (stride-4 -> 2-way, free).
#define COLU4 3   // uint4 slots per column (2 data + 1 pad)

__device__ __forceinline__ h2 as_h2(u32 u) { union { u32 u; h2 h; } x; x.u = u; return x.h; }

__global__ __launch_bounds__(256) void dtw_wavefront(
    const float* __restrict__ x,      // (16, 16, 1024)
    const float* __restrict__ patts,  // (64, 16, 64)
    float* __restrict__ out,          // (16, 64, 64, 64)
    float w) {
  __shared__ uint4 xs4[T_LEN * COLU4];   // 48 KiB
  __shared__ float x2a[T_LEN];           // 4 KiB

  const int tid  = threadIdx.x;
  const int lane = tid & 63;
  const int wv   = tid >> 6;
  const int b    = blockIdx.x >> 4;
  const int p    = (blockIdx.x & 15) * 4 + wv;

  // ---- stage x[b]: f16-pack columns + f32 x2 ----
  const float* xb = x + b * (16 * T_LEN);
  for (int t = tid; t < T_LEN; t += 256) {
    float v[16]; float s2 = 0.f;
    #pragma unroll
    for (int dd = 0; dd < 16; ++dd) { float f = xb[dd * T_LEN + t]; v[dd] = f; s2 = fmaf(f, f, s2); }
    u32 pk[8];
    #pragma unroll
    for (int j = 0; j < 8; ++j) {
      union { _Float16 h[2]; u32 u; } c;
      c.h[0] = (_Float16)v[2*j]; c.h[1] = (_Float16)v[2*j+1];
      pk[j] = c.u;
    }
    xs4[t*COLU4]   = make_uint4(pk[0], pk[1], pk[2], pk[3]);
    xs4[t*COLU4+1] = make_uint4(pk[4], pk[5], pk[6], pk[7]);
    x2a[t] = s2;
  }
  __syncthreads();

  // ---- lane-resident pattern column p[:, lane] in f16 pairs ----
  const float* pp = patts + p * (16 * L_LEN);
  h2 pv[8]; float p2 = 0.f;
  #pragma unroll
  for (int j = 0; j < 8; ++j) {
    float f0 = pp[(2*j) * L_LEN + lane];
    float f1 = pp[(2*j+1) * L_LEN + lane];
    p2 = fmaf(f0, f0, fmaf(f1, f1, p2));
    h2 h; h.x = (_Float16)f0; h.y = (_Float16)f1;
    pv[j] = h;
  }
  const float nhp2 = -0.5f * p2;     // folded into dot chain0 init: sq = x2 + p2 - 2*dot
  const int bigbits = __float_as_int(BIGV);

  float* op = out + ((b * 64 + p) * 64 + lane) * 64;

  float prev = BIGV, shA = BIGV, shB = BIGV;

  uint4 q0[4], q1[4]; float cx2[4];

  // clamped column load (prologue/epilogue)
  #define LOADC(j, tt) do { int tc_ = (tt); tc_ = tc_ < 0 ? 0 : (tc_ > T_LEN-1 ? T_LEN-1 : tc_); \
      q0[j] = xs4[tc_*COLU4]; q1[j] = xs4[tc_*COLU4+1]; cx2[j] = x2a[tc_]; } while (0)

  #define DOT_DIST(j, distv) \
      float c0_ = __builtin_amdgcn_fdot2(as_h2(q0[j].x), pv[0], nhp2, false); \
      float c1_ = __builtin_amdgcn_fdot2(as_h2(q0[j].y), pv[1], 0.f,  false); \
      c0_ = __builtin_amdgcn_fdot2(as_h2(q0[j].z), pv[2], c0_, false); \
      c1_ = __builtin_amdgcn_fdot2(as_h2(q0[j].w), pv[3], c1_, false); \
      c0_ = __builtin_amdgcn_fdot2(as_h2(q1[j].x), pv[4], c0_, false); \
      c1_ = __builtin_amdgcn_fdot2(as_h2(q1[j].y), pv[5], c1_, false); \
      c0_ = __builtin_amdgcn_fdot2(as_h2(q1[j].z), pv[6], c0_, false); \
      c1_ = __builtin_amdgcn_fdot2(as_h2(q1[j].w), pv[7], c1_, false); \
      float sq_ = fmaf(-2.f, c0_ + c1_, cx2[j]); \
      float distv = __builtin_amdgcn_sqrtf(fmaxf(sq_, 1e-12f));

  #define SHIFT(curv) do { \
      int sh_ = __builtin_amdgcn_update_dpp(bigbits, __float_as_int(curv), 0x138, 0xF, 0xF, false); \
      shB = shA; shA = __int_as_float(sh_); prev = (curv); } while (0)

  // ================= prologue: s in [0, 64), BIG-check + low-range mask =================
  #pragma unroll
  for (int j = 0; j < 4; ++j) LOADC(j, j - lane);
  for (int s = 0; s < 64; s += 4) {
    #pragma unroll
    for (int j = 0; j < 4; ++j) {
      const int t = s + j - lane;
      DOT_DIST(j, dist);
      LOADC(j, t + 4);
      float m    = fminf(fminf(prev, shA), shB);
      float msel = (m >= 0.5e30f) ? 0.f : m;
      float val  = fmaf(w, msel, dist);
      float cur  = (t >= 0) ? val : BIGV;
      SHIFT(cur);
    }
  }

  // ================= main: s in [64, 960), no boundary cases =================
  {
    const char* xsb = (const char*)xs4;
    const char* x2b = (const char*)x2a;
    int bo = (64 - lane) * 48;
    int xo = (64 - lane) * 4;
    #pragma unroll
    for (int j = 0; j < 4; ++j) {
      q0[j] = *(const uint4*)(xsb + bo + j*48);
      q1[j] = *(const uint4*)(xsb + bo + j*48 + 16);
      cx2[j] = *(const float*)(x2b + xo + j*4);
    }
    for (int s = 64; s < 960; s += 4) {
      #pragma unroll
      for (int j = 0; j < 4; ++j) {
        DOT_DIST(j, dist);
        q0[j]  = *(const uint4*)(xsb + bo + (j+4)*48);
        q1[j]  = *(const uint4*)(xsb + bo + (j+4)*48 + 16);
        cx2[j] = *(const float*)(x2b + xo + (j+4)*4);
        float m   = fminf(fminf(prev, shA), shB);   // provably < BIG here
        float cur = fmaf(w, m, dist);
        SHIFT(cur);
      }
      bo += 192; xo += 16;
    }
  }

  // ================= epilogue: s in [960, 1088), high-range mask + stores =================
  #pragma unroll
  for (int j = 0; j < 4; ++j) LOADC(j, 960 + j - lane);
  for (int s = 960; s < 1088; s += 4) {
    #pragma unroll
    for (int j = 0; j < 4; ++j) {
      const int t = s + j - lane;
      DOT_DIST(j, dist);
      LOADC(j, t + 4);
      float m   = fminf(fminf(prev, shA), shB);
      float val = fmaf(w, m, dist);
      float cur = (t < T_LEN) ? val : BIGV;
      if ((u32)(t - (T_LEN - L_LEN)) < (u32)L_LEN) op[t - (T_LEN - L_LEN)] = val;
      SHIFT(cur);
    }
  }
}

extern "C" void kernel_launch(void* const* d_in, const int* in_sizes, int n_in,
                              void* d_out, int out_size, void* d_ws, size_t ws_size,
                              hipStream_t stream) {
  const float* x     = (const float*)d_in[0];
  const float* patts = (const float*)d_in[1];
  float* out         = (float*)d_out;
  const float w = (float)exp(log(0.1) / 64.0);
  dim3 grid(256), block(256);
  hipLaunchKernelGGL(dtw_wavefront, grid, block, 0, stream, x, patts, out, w);
}